// Round 11
// baseline (427.006 us; speedup 1.0000x reference)
//
#include <hip/hip_runtime.h>
#include <math.h>

#define N_NODES 50000
#define N_EDGES 800000
#define DIN 256
#define DHID 128
#define DOUT 64
// Padded CSR row stride. In-degree ~ Poisson(16); P(deg > 64) ~ 1e-19 -> safe.
#define CSTRIDE 64
#define ZROW N_NODES            // sentinel row (kept zero)
#define HBLOCKS 128
#define HCHUNK (N_EDGES / HBLOCKS)     // 6250
#define HWORDS (N_NODES / 4)           // 12500
#define SLICE ((size_t)(N_NODES + 1) * 16)
#define NGROUPS (N_NODES / 4)          // 12500
#define P2BLOCKS 196                   // hpre/dscatter blocks (12500/64 word-cols)
#define GROWB 782                      // gemm row-tiles (64 rows each)

// ---------------- fat setup kernel: sentinel-fill csr, 2 histograms, weight folds ----
#define SB_SENT 3125
#define SB_HS (SB_SENT + HBLOCKS)       // 3253
#define SB_HD (SB_HS + HBLOCKS)         // 3381
#define SB_TOT (SB_HD + 66)             // 3447

__global__ void k_setup(const int* __restrict__ src, const int* __restrict__ dst,
                        unsigned int* __restrict__ pS, unsigned int* __restrict__ pD,
                        unsigned int* __restrict__ csr32,
                        const float* __restrict__ W1, const float* __restrict__ b1,
                        const float* __restrict__ W3,
                        float* __restrict__ W13, float* __restrict__ bb,
                        float* __restrict__ Y0, float* __restrict__ Y1) {
    __shared__ unsigned int h[HWORDS];
    int bx = blockIdx.x, t = threadIdx.x;
    if (bx < SB_SENT) {
        // pre-fill every csr slot with the sentinel (k_fill overwrites [0,deg))
        unsigned int v = (unsigned int)ZROW | ((unsigned int)ZROW << 16);
        uint2 o; o.x = v; o.y = v;
        ((uint2*)csr32)[bx * 256 + t] = o;
        return;
    }
    if (bx < SB_HD) {
        // byte-packed LDS-privatized histogram (4 bins per u32); per-block
        // per-node counts <= total degree (<=64) << 255 -> no byte carry.
        const int* idx = (bx < SB_HS) ? src : dst;
        unsigned int* outp = (bx < SB_HS) ? pS : pD;
        int hb = bx - ((bx < SB_HS) ? SB_SENT : SB_HS);
        for (int w = t; w < HWORDS; w += 256) h[w] = 0u;
        __syncthreads();
        int base = hb * HCHUNK;
        for (int i = t; i < HCHUNK; i += 256) {
            int s = idx[base + i];
            atomicAdd(&h[s >> 2], 1u << ((s & 3) << 3));
        }
        __syncthreads();
        outp += (size_t)hb * HWORDS;
        for (int w = t; w < HWORDS; w += 256) outp[w] = h[w];
        return;
    }
    int vb = bx - SB_HD;                 // 0..65
    if (vb == 65) {
        if (t < 64) {                    // zero the sentinel row in both buffers
            int qq = t >> 4, c2 = t & 15;
            Y0[(size_t)qq * SLICE + ((size_t)ZROW << 4) + c2] = 0.f;
            Y1[(size_t)qq * SLICE + ((size_t)ZROW << 4) + c2] = 0.f;
        }
        return;
    }
    if (vb == 64) {
        if (t < DOUT) {
            float s = 0.f;
            for (int k = 0; k < DHID; ++k) s += b1[k] * W3[k * DOUT + t];
            bb[t] = s;
        }
        return;
    }
    int idx2 = vb * 256 + t;             // 16384 outputs of W13 = W1@W3
    int i = idx2 >> 6, j = idx2 & 63;
    float s = 0.f;
    for (int k = 0; k < DHID; ++k) s += W1[i * DHID + k] * W3[k * DOUT + j];
    W13[idx2] = s;
}

// ---------------- hpre: 4-way-parallel scan + reduce + norms + degree hist ----------------
// thread = (col, sub): col = t>>2 owns packed word wid, sub = t&3 scans 32 of
// the 128 hist blocks. Packed byte sums never carry (per-node totals <= 64).
__global__ void k_hpre(const unsigned int* __restrict__ pS,
                       const unsigned int* __restrict__ pD,
                       unsigned int* __restrict__ prefix,
                       int* __restrict__ deg_in,
                       float* __restrict__ ns, float* __restrict__ nd,
                       float* __restrict__ cc, int* __restrict__ dparts) {
    __shared__ unsigned int sdw[64][4];
    __shared__ unsigned int sow[64][4];
    __shared__ int lh[65];
    int t = threadIdx.x;
    if (t < 65) lh[t] = 0;
    int col = t >> 2, sub = t & 3;
    int wid = blockIdx.x * 64 + col;
    bool act = wid < HWORDS;
    unsigned int ps = 0, pd = 0;
    if (act) {
        int b0 = sub << 5;
#pragma unroll 4
        for (int b = b0; b < b0 + 32; ++b) {
            ps += pS[(size_t)b * HWORDS + wid];
            pd += pD[(size_t)b * HWORDS + wid];
        }
    }
    sdw[col][sub] = pd;
    sow[col][sub] = ps;
    __syncthreads();
    if (act) {
        unsigned int base = 0;
        for (int k = 0; k < sub; ++k) base += sdw[col][k];
        int b0 = sub << 5;
        unsigned int run = base;
        for (int b = b0; b < b0 + 32; ++b) {
            unsigned int w = pD[(size_t)b * HWORDS + wid];
            prefix[(size_t)b * HWORDS + wid] = run;
            run += w;
        }
        if (sub == 0) {
            unsigned int totd = sdw[col][0] + sdw[col][1] + sdw[col][2] + sdw[col][3];
            unsigned int toto = sow[col][0] + sow[col][1] + sow[col][2] + sow[col][3];
            unsigned int di[4] = {totd & 0xffu, (totd >> 8) & 0xffu,
                                  (totd >> 16) & 0xffu, totd >> 24};
            unsigned int dov[4] = {toto & 0xffu, (toto >> 8) & 0xffu,
                                   (toto >> 16) & 0xffu, toto >> 24};
            int4 dd; dd.x = (int)di[0]; dd.y = (int)di[1]; dd.z = (int)di[2]; dd.w = (int)di[3];
            *(int4*)(deg_in + (wid << 2)) = dd;
            float4 vns, vnd, vcc;
            float* pns = &vns.x; float* pnd = &vnd.x; float* pcc = &vcc.x;
#pragma unroll
            for (int q = 0; q < 4; ++q) {
                int bin = (int)di[q]; if (bin > 64) bin = 64;
                atomicAdd(&lh[bin], 1);
                unsigned int a = dov[q] < 1u ? 1u : dov[q];
                unsigned int b = di[q] < 1u ? 1u : di[q];
                float fa = 1.0f / sqrtf((float)a);
                float fb = 1.0f / sqrtf((float)b);
                pns[q] = fa; pnd[q] = fb; pcc[q] = fa * fb;
            }
            *(float4*)(ns + (wid << 2)) = vns;
            *(float4*)(nd + (wid << 2)) = vnd;
            *(float4*)(cc + (wid << 2)) = vcc;
        }
    }
    __syncthreads();
    if (t < 65) dparts[blockIdx.x * 65 + t] = lh[t];
}

// ---------------- counting-sort scan (DESCENDING degree) ----------------
__global__ void k_dscan(const int* __restrict__ dparts, int* __restrict__ offs) {
    __shared__ int colsum[65], binbase[65];
    int t = threadIdx.x;
    if (t < 65) {
        int s = 0;
        for (int b = 0; b < P2BLOCKS; ++b) s += dparts[b * 65 + t];
        colsum[t] = s;
    }
    __syncthreads();
    if (t == 0) {
        int run = 0;
        for (int k = 64; k >= 0; --k) { binbase[k] = run; run += colsum[k]; }
    }
    __syncthreads();
    if (t < 65) {
        int run = binbase[t];
        for (int b = 0; b < P2BLOCKS; ++b) { offs[b * 65 + t] = run; run += dparts[b * 65 + t]; }
    }
}

// ---------------- scatter: perm/inv + permuted degree & norm arrays ----------------
__global__ void k_dscatter(const int* __restrict__ deg_in, const int* __restrict__ offs,
                           const float* __restrict__ cc, const float* __restrict__ ns,
                           const float* __restrict__ nd,
                           int* __restrict__ perm, int* __restrict__ inv,
                           int* __restrict__ degP, float* __restrict__ ccP,
                           float* __restrict__ nsP, float* __restrict__ ndP) {
    __shared__ int off[65];
    int t = threadIdx.x;
    if (t < 65) off[t] = offs[blockIdx.x * 65 + t];
    __syncthreads();
    int wid = blockIdx.x * 64 + t;
    if (t < 64 && wid < HWORDS) {
        int4 d4 = *(const int4*)(deg_in + (wid << 2));
        int dd[4] = {d4.x, d4.y, d4.z, d4.w};
#pragma unroll
        for (int k = 0; k < 4; ++k) {
            int node = (wid << 2) + k;
            int bin = dd[k] > 64 ? 64 : dd[k];
            int slot = atomicAdd(&off[bin], 1);
            perm[slot] = node; inv[node] = slot;
            degP[slot] = dd[k];
            ccP[slot] = cc[node]; nsP[slot] = ns[node]; ndP[slot] = nd[node];
        }
    }
}

// ---------------- fill csr (renumbered space) using LDS atomics only ----------------
__global__ void k_fill(const int* __restrict__ src, const int* __restrict__ dst,
                       const unsigned int* __restrict__ prefix,
                       const int* __restrict__ inv,
                       unsigned short* __restrict__ csr) {
    __shared__ unsigned int h[HWORDS];
    int t = threadIdx.x;
    const unsigned int* prow = prefix + (size_t)blockIdx.x * HWORDS;
    for (int w = t; w < HWORDS; w += 256) h[w] = prow[w];
    __syncthreads();
    int base = blockIdx.x * HCHUNK;
    for (int i = t; i < HCHUNK; i += 256) {
        int s = src[base + i], d = dst[base + i];
        int sh = (d & 3) << 3;
        unsigned int old = atomicAdd(&h[d >> 2], 1u << sh);
        int slot = (int)((old >> sh) & 0xffu);
        csr[((size_t)inv[d] << 6) + slot] = (unsigned short)inv[s];
    }
}

// ---------------- dense GEMM, K-split-2 + double-buffered LDS ----------------
// Block bx<GROWB computes rows bx*64, K=[0,128) into P0; bx>=GROWB same rows,
// K=[128,256) into P1. Single __syncthreads per 16-k chunk; next chunk's
// global loads issued into registers while computing the current chunk.
__launch_bounds__(256, 8)
__global__ void k_gemm(const float* __restrict__ X, const float* __restrict__ W13,
                       float* __restrict__ P0, float* __restrict__ P1) {
    __shared__ float As[2][16][68];
    __shared__ float Bs[2][16][64];
    int tid = threadIdx.x;
    int half = blockIdx.x >= GROWB;
    int bx = half ? (blockIdx.x - GROWB) : blockIdx.x;
    float* P = half ? P1 : P0;
    int kbase = half << 7;               // 0 or 128
    int tx = tid & 15, ty = tid >> 4;
    int row0 = bx * 64;
    float acc[4][4];
#pragma unroll
    for (int i = 0; i < 4; ++i)
#pragma unroll
        for (int j = 0; j < 4; ++j) acc[i][j] = 0.f;

    int lr = tid >> 2;
    int lk = (tid & 3) << 2;
    int arow = row0 + lr;
    if (arow > N_NODES - 1) arow = N_NODES - 1;   // clamp: garbage rows never stored
    const float* Xr = X + (size_t)arow * DIN + kbase + lk;
    const float* Wr = W13 + (size_t)(kbase + ty) * DOUT + (tx << 2);

    float4 a_nxt = *(const float4*)Xr;
    float4 b_nxt = *(const float4*)Wr;
    for (int c = 0; c < 8; ++c) {
        int buf = c & 1;
        As[buf][lk + 0][lr] = a_nxt.x; As[buf][lk + 1][lr] = a_nxt.y;
        As[buf][lk + 2][lr] = a_nxt.z; As[buf][lk + 3][lr] = a_nxt.w;
        *(float4*)&Bs[buf][ty][tx << 2] = b_nxt;
        __syncthreads();
        if (c < 7) {
            a_nxt = *(const float4*)(Xr + ((c + 1) << 4));
            b_nxt = *(const float4*)(Wr + (size_t)((c + 1) << 4) * DOUT);
        }
#pragma unroll
        for (int k = 0; k < 16; ++k) {
            float4 av = *(const float4*)&As[buf][k][ty << 2];
            float4 bv = *(const float4*)&Bs[buf][k][tx << 2];
            float ar[4] = {av.x, av.y, av.z, av.w};
            float br[4] = {bv.x, bv.y, bv.z, bv.w};
#pragma unroll
            for (int i = 0; i < 4; ++i)
#pragma unroll
                for (int j = 0; j < 4; ++j) acc[i][j] += ar[i] * br[j];
        }
    }
#pragma unroll
    for (int i = 0; i < 4; ++i) {
        int row = row0 + (ty << 2) + i;
        if (row < N_NODES) {
            float4 o; o.x = acc[i][0]; o.y = acc[i][1]; o.z = acc[i][2]; o.w = acc[i][3];
            *(float4*)(P + (size_t)row * DOUT + (tx << 2)) = o;
        }
    }
}

// ---------------- combine: Y0[inv[row]] = ns[row]*(P0+P1), COLUMN-SLICED ----------------
__global__ void k_comb(const float* __restrict__ P0, const float* __restrict__ P1,
                       const float* __restrict__ ns, const int* __restrict__ inv,
                       float* __restrict__ Y) {
    int idx = blockIdx.x * 256 + threadIdx.x;    // 800000 float4s
    int row = idx >> 4;
    int p = idx & 15;                            // cols 4p..4p+3
    float4 a = ((const float4*)P0)[idx];
    float4 b = ((const float4*)P1)[idx];
    float nsr = ns[row];
    int prow = inv[row];
    int q = p >> 2, co = (p & 3) << 2;
    float4 o;
    o.x = (a.x + b.x) * nsr; o.y = (a.y + b.y) * nsr;
    o.z = (a.z + b.z) * nsr; o.w = (a.w + b.w) * nsr;
    *(float4*)(Y + (size_t)q * SLICE + ((size_t)prow << 4) + co) = o;
}

// ---------------- sliced pull SpMM, degree-sorted: 4 nodes x 4 edge-slots x float4 ------
// Loop bound m = pad4(degP[node0]) (group max, descending sort). Wave-uniform m
// branches to fully-unrolled paths (all gathers issued back-to-back, <=8 in
// flight). LDS rows TRANSPOSED [entry*4 + node] -> conflict-free ds_read_u16.
// MODE 0: y = cc*acc + ns*bb[col]; MODE 1: y = cc*acc;
// MODE 2: out[perm[node]] = nd*acc + b3[col]  (row-major, original numbering).

template <int MODE>
__launch_bounds__(256, 8)
__global__ void k_spmm(const float* __restrict__ xs, float* __restrict__ ys,
                       const unsigned short* __restrict__ csr,
                       const int* __restrict__ degP,
                       const float* __restrict__ ccP, const float* __restrict__ nsP,
                       const float* __restrict__ ndP,
                       const float* __restrict__ bb, const float* __restrict__ b3,
                       const int* __restrict__ perm) {
    __shared__ unsigned short rows[4][256];     // [wave][entry*4 + node] = 2 KB
    int wid  = threadIdx.x >> 6;
    int lane = threadIdx.x & 63;
    int q    = (blockIdx.x & 7) >> 1;
    int half = blockIdx.x & 1;
    int g    = (blockIdx.x >> 3) * 8 + wid * 2 + half;   // 4-node group id
    if (g >= NGROUPS) return;
    int node0 = g << 2;

    // stage 4 csr rows (4 x 128 B) into LDS, transposed: lane (nn,sl) loads
    // entries 4sl..4sl+3 of node nn and writes them at [(4sl+k)*4 + nn].
    int nn = lane >> 4, sl = lane & 15;
    const uint2* crow = (const uint2*)(csr + ((size_t)(node0 + nn) << 6)) + sl;
    uint2 rv = *crow;
    unsigned short* bp = &rows[wid][(sl << 4) + nn];
    bp[0]  = (unsigned short)(rv.x & 0xffffu);
    bp[4]  = (unsigned short)(rv.x >> 16);
    bp[8]  = (unsigned short)(rv.y & 0xffffu);
    bp[12] = (unsigned short)(rv.y >> 16);

    int n0u = __builtin_amdgcn_readfirstlane(node0);
    int m = (degP[n0u] + 3) & ~3;        // group max (descending sort), pad4

    int n = lane >> 4, e = (lane >> 2) & 3, c4 = lane & 3;
    const unsigned short* rd = &rows[wid][(e << 2) + n];   // entry (e+4T) at rd[16T]
    const float* xq = xs + (size_t)q * SLICE + (c4 << 2);

    float ax = 0.f, ay = 0.f, az = 0.f, aw = 0.f;
#define LDV(T) const float4 v##T = *(const float4*)(xq + ((size_t)rd[16 * (T)] << 4))
#define ACCV(T) ax += v##T.x; ay += v##T.y; az += v##T.z; aw += v##T.w
    if (m <= 4) {
        LDV(0); ACCV(0);
    } else if (m <= 8) {
        LDV(0); LDV(1);
        ACCV(0); ACCV(1);
    } else if (m <= 12) {
        LDV(0); LDV(1); LDV(2);
        ACCV(0); ACCV(1); ACCV(2);
    } else if (m <= 16) {
        LDV(0); LDV(1); LDV(2); LDV(3);
        ACCV(0); ACCV(1); ACCV(2); ACCV(3);
    } else if (m <= 20) {
        LDV(0); LDV(1); LDV(2); LDV(3); LDV(4);
        ACCV(0); ACCV(1); ACCV(2); ACCV(3); ACCV(4);
    } else if (m <= 24) {
        LDV(0); LDV(1); LDV(2); LDV(3); LDV(4); LDV(5);
        ACCV(0); ACCV(1); ACCV(2); ACCV(3); ACCV(4); ACCV(5);
    } else if (m <= 28) {
        LDV(0); LDV(1); LDV(2); LDV(3); LDV(4); LDV(5); LDV(6);
        ACCV(0); ACCV(1); ACCV(2); ACCV(3); ACCV(4); ACCV(5); ACCV(6);
    } else if (m <= 32) {
        LDV(0); LDV(1); LDV(2); LDV(3); LDV(4); LDV(5); LDV(6); LDV(7);
        ACCV(0); ACCV(1); ACCV(2); ACCV(3); ACCV(4); ACCV(5); ACCV(6); ACCV(7);
    } else {
        for (int j2 = 0; j2 < m; j2 += 4) {
            const float4 a = *(const float4*)(xq + ((size_t)rd[j2 << 2] << 4));
            ax += a.x; ay += a.y; az += a.z; aw += a.w;
        }
    }
#undef LDV
#undef ACCV
    // reduce over edge-slots e (lane bits 2..3)
    ax += __shfl_xor(ax, 4);  ay += __shfl_xor(ay, 4);
    az += __shfl_xor(az, 4);  aw += __shfl_xor(aw, 4);
    ax += __shfl_xor(ax, 8);  ay += __shfl_xor(ay, 8);
    az += __shfl_xor(az, 8);  aw += __shfl_xor(aw, 8);

    int nodeL = node0 + n;
    int colq  = (q << 4) + (c4 << 2);
    float4 r;
    if (MODE == 0) {
        float cv = ccP[nodeL], nv = nsP[nodeL];
        float4 bv = *(const float4*)(bb + colq);
        r.x = cv * ax + nv * bv.x; r.y = cv * ay + nv * bv.y;
        r.z = cv * az + nv * bv.z; r.w = cv * aw + nv * bv.w;
    } else if (MODE == 1) {
        float cv = ccP[nodeL];
        r.x = cv * ax; r.y = cv * ay; r.z = cv * az; r.w = cv * aw;
    } else {
        float dv = ndP[nodeL];
        float4 bv = *(const float4*)(b3 + colq);
        r.x = dv * ax + bv.x; r.y = dv * ay + bv.y;
        r.z = dv * az + bv.z; r.w = dv * aw + bv.w;
    }
    if (e == 0) {
        if (MODE == 2) {
            int orow = perm[nodeL];
            *(float4*)(ys + ((size_t)orow << 6) + colq) = r;
        } else {
            *(float4*)(ys + (size_t)q * SLICE + ((size_t)nodeL << 4) + (c4 << 2)) = r;
        }
    }
}

// ---------------- launcher ----------------

extern "C" void kernel_launch(void* const* d_in, const int* in_sizes, int n_in,
                              void* d_out, int out_size, void* d_ws, size_t ws_size,
                              hipStream_t stream) {
    const float* X   = (const float*)d_in[0];
    const int*   src = (const int*)d_in[1];
    const int*   dst = (const int*)d_in[2];
    const float* W1  = (const float*)d_in[3];
    const float* b1  = (const float*)d_in[4];
    const float* W3  = (const float*)d_in[5];
    const float* b3  = (const float*)d_in[6];
    float* out = (float*)d_out;

    char* ws = (char*)d_ws;
    size_t off = 0;
    auto alloc = [&](size_t bytes) -> void* {
        void* p = ws + off;
        off = (off + bytes + 255) & ~(size_t)255;
        return p;
    };
    unsigned int*   pS     = (unsigned int*)alloc((size_t)HBLOCKS * HWORDS * 4);  // 6.4 MB
    unsigned int*   pD     = (unsigned int*)alloc((size_t)HBLOCKS * HWORDS * 4);  // 6.4 MB
    unsigned int*   pref   = (unsigned int*)alloc((size_t)HBLOCKS * HWORDS * 4);  // 6.4 MB
    float*          Y0     = (float*)alloc(SLICE * 4 * 4);
    float*          Y1     = (float*)alloc(SLICE * 4 * 4);
    float*          P0     = (float*)alloc((size_t)N_NODES * DOUT * 4);           // 12.8 MB
    float*          P1     = (float*)alloc((size_t)N_NODES * DOUT * 4);           // 12.8 MB
    unsigned short* csr    = (unsigned short*)alloc((size_t)N_NODES * CSTRIDE * 2);
    int*            deg_in = (int*)alloc((size_t)N_NODES * 4);
    float*          ns     = (float*)alloc((size_t)N_NODES * 4);
    float*          nd     = (float*)alloc((size_t)N_NODES * 4);
    float*          cc     = (float*)alloc((size_t)N_NODES * 4);
    int*            perm   = (int*)alloc((size_t)N_NODES * 4);
    int*            inv    = (int*)alloc((size_t)N_NODES * 4);
    int*            degP   = (int*)alloc((size_t)N_NODES * 4);
    float*          ccP    = (float*)alloc((size_t)N_NODES * 4);
    float*          nsP    = (float*)alloc((size_t)N_NODES * 4);
    float*          ndP    = (float*)alloc((size_t)N_NODES * 4);
    int*            dparts = (int*)alloc((size_t)P2BLOCKS * 65 * 4);
    int*            offs   = (int*)alloc((size_t)P2BLOCKS * 65 * 4);
    float*          W13    = (float*)alloc((size_t)DIN * DOUT * 4);
    float*          bb     = (float*)alloc(DOUT * 4);

    const int sblk = 1563 * 8;   // 12504 blocks -> 12500 groups x 4 slices

    k_setup<<<SB_TOT, 256, 0, stream>>>(src, dst, pS, pD, (unsigned int*)csr,
                                        W1, b1, W3, W13, bb, Y0, Y1);
    k_hpre<<<P2BLOCKS, 256, 0, stream>>>(pS, pD, pref, deg_in, ns, nd, cc, dparts);
    k_dscan<<<1, 128, 0, stream>>>(dparts, offs);
    k_dscatter<<<P2BLOCKS, 128, 0, stream>>>(deg_in, offs, cc, ns, nd,
                                             perm, inv, degP, ccP, nsP, ndP);
    k_fill<<<HBLOCKS, 256, 0, stream>>>(src, dst, pref, inv, csr);

    // P0/P1 = X @ W13 (K halves); Y0 = ns ∘ (P0+P1), column-sliced, renumbered
    k_gemm<<<GROWB * 2, 256, 0, stream>>>(X, W13, P0, P1);
    k_comb<<<(N_NODES * DOUT / 4) / 256, 256, 0, stream>>>(P0, P1, ns, inv, Y0);

    // 6 propagation passes; bias bb injected in pass 1, b3 in pass 6
    k_spmm<0><<<sblk, 256, 0, stream>>>(Y0, Y1, csr, degP, ccP, nsP, ndP, bb, b3, perm);
    k_spmm<1><<<sblk, 256, 0, stream>>>(Y1, Y0, csr, degP, ccP, nsP, ndP, bb, b3, perm);
    k_spmm<1><<<sblk, 256, 0, stream>>>(Y0, Y1, csr, degP, ccP, nsP, ndP, bb, b3, perm);
    k_spmm<1><<<sblk, 256, 0, stream>>>(Y1, Y0, csr, degP, ccP, nsP, ndP, bb, b3, perm);
    k_spmm<1><<<sblk, 256, 0, stream>>>(Y0, Y1, csr, degP, ccP, nsP, ndP, bb, b3, perm);
    k_spmm<2><<<sblk, 256, 0, stream>>>(Y1, out, csr, degP, ccP, nsP, ndP, bb, b3, perm);
}

// Round 12
// 313.564 us; speedup vs baseline: 1.3618x; 1.3618x over previous
//
#include <hip/hip_runtime.h>
#include <math.h>

#define N_NODES 50000
#define N_EDGES 800000
#define DIN 256
#define DHID 128
#define DOUT 64
// Padded CSR row stride. In-degree ~ Poisson(16); P(deg > 64) ~ 1e-19 -> safe.
#define CSTRIDE 64
#define ZROW N_NODES            // sentinel row (kept zero)
#define HBLOCKS 256
#define HCHUNK (N_EDGES / HBLOCKS)     // 3125
#define HWORDS (N_NODES / 4)           // 12500
#define SLICE ((size_t)(N_NODES + 1) * 16)
#define NGROUPS (N_NODES / 4)          // 12500
#define P2BLOCKS 196                   // hpre/dscatter blocks (12500/64 word-cols)

// ---------------- fat setup kernel: sentinel-fill csr, 2 histograms, weight folds ----
#define SB_SENT 3125
#define SB_HS (SB_SENT + HBLOCKS)       // 3381
#define SB_HD (SB_HS + HBLOCKS)         // 3637
#define SB_TOT (SB_HD + 66)             // 3703

__global__ void k_setup(const int* __restrict__ src, const int* __restrict__ dst,
                        unsigned int* __restrict__ pS, unsigned int* __restrict__ pD,
                        unsigned int* __restrict__ csr32,
                        const float* __restrict__ W1, const float* __restrict__ b1,
                        const float* __restrict__ W3,
                        float* __restrict__ W13, float* __restrict__ bb,
                        float* __restrict__ Y0, float* __restrict__ Y1) {
    __shared__ unsigned int h[HWORDS];
    int bx = blockIdx.x, t = threadIdx.x;
    if (bx < SB_SENT) {
        // pre-fill every csr slot with the sentinel (k_fill overwrites [0,deg))
        unsigned int v = (unsigned int)ZROW | ((unsigned int)ZROW << 16);
        uint2 o; o.x = v; o.y = v;
        ((uint2*)csr32)[bx * 256 + t] = o;
        return;
    }
    if (bx < SB_HD) {
        // byte-packed LDS-privatized histogram (4 bins per u32); per-block
        // per-node counts <= total degree (<=64) << 255 -> no byte carry.
        const int* idx = (bx < SB_HS) ? src : dst;
        unsigned int* outp = (bx < SB_HS) ? pS : pD;
        int hb = bx - ((bx < SB_HS) ? SB_SENT : SB_HS);
        for (int w = t; w < HWORDS; w += 256) h[w] = 0u;
        __syncthreads();
        int base = hb * HCHUNK;
        for (int i = t; i < HCHUNK; i += 256) {
            int s = idx[base + i];
            atomicAdd(&h[s >> 2], 1u << ((s & 3) << 3));
        }
        __syncthreads();
        outp += (size_t)hb * HWORDS;
        for (int w = t; w < HWORDS; w += 256) outp[w] = h[w];
        return;
    }
    int vb = bx - SB_HD;                 // 0..65
    if (vb == 65) {
        if (t < 64) {                    // zero the sentinel row in both buffers
            int qq = t >> 4, c2 = t & 15;
            Y0[(size_t)qq * SLICE + ((size_t)ZROW << 4) + c2] = 0.f;
            Y1[(size_t)qq * SLICE + ((size_t)ZROW << 4) + c2] = 0.f;
        }
        return;
    }
    if (vb == 64) {
        if (t < DOUT) {
            float s = 0.f;
            for (int k = 0; k < DHID; ++k) s += b1[k] * W3[k * DOUT + t];
            bb[t] = s;
        }
        return;
    }
    int idx2 = vb * 256 + t;             // 16384 outputs of W13 = W1@W3
    int i = idx2 >> 6, j = idx2 & 63;
    float s = 0.f;
    for (int k = 0; k < DHID; ++k) s += W1[i * DHID + k] * W3[k * DOUT + j];
    W13[idx2] = s;
}

// ---------------- hpre: 4-way-parallel scan + reduce + norms + degree hist ----------------
// thread = (col, sub): col = t>>2 owns packed word wid, sub = t&3 scans 64 of
// the 256 hist blocks. Packed byte sums never carry (per-node totals <= 64).
__global__ void k_hpre(const unsigned int* __restrict__ pS,
                       const unsigned int* __restrict__ pD,
                       unsigned int* __restrict__ prefix,
                       int* __restrict__ deg_in,
                       float* __restrict__ ns, float* __restrict__ nd,
                       float* __restrict__ cc, int* __restrict__ dparts) {
    __shared__ unsigned int sdw[64][4];
    __shared__ unsigned int sow[64][4];
    __shared__ int lh[65];
    int t = threadIdx.x;
    if (t < 65) lh[t] = 0;
    int col = t >> 2, sub = t & 3;
    int wid = blockIdx.x * 64 + col;
    bool act = wid < HWORDS;
    unsigned int ps = 0, pd = 0;
    if (act) {
        int b0 = sub << 6;
#pragma unroll 4
        for (int b = b0; b < b0 + 64; ++b) {
            ps += pS[(size_t)b * HWORDS + wid];
            pd += pD[(size_t)b * HWORDS + wid];
        }
    }
    sdw[col][sub] = pd;
    sow[col][sub] = ps;
    __syncthreads();
    if (act) {
        unsigned int base = 0;
        for (int k = 0; k < sub; ++k) base += sdw[col][k];
        int b0 = sub << 6;
        unsigned int run = base;
        for (int b = b0; b < b0 + 64; ++b) {
            unsigned int w = pD[(size_t)b * HWORDS + wid];
            prefix[(size_t)b * HWORDS + wid] = run;
            run += w;
        }
        if (sub == 0) {
            unsigned int totd = sdw[col][0] + sdw[col][1] + sdw[col][2] + sdw[col][3];
            unsigned int toto = sow[col][0] + sow[col][1] + sow[col][2] + sow[col][3];
            unsigned int di[4] = {totd & 0xffu, (totd >> 8) & 0xffu,
                                  (totd >> 16) & 0xffu, totd >> 24};
            unsigned int dov[4] = {toto & 0xffu, (toto >> 8) & 0xffu,
                                   (toto >> 16) & 0xffu, toto >> 24};
            int4 dd; dd.x = (int)di[0]; dd.y = (int)di[1]; dd.z = (int)di[2]; dd.w = (int)di[3];
            *(int4*)(deg_in + (wid << 2)) = dd;
            float4 vns, vnd, vcc;
            float* pns = &vns.x; float* pnd = &vnd.x; float* pcc = &vcc.x;
#pragma unroll
            for (int q = 0; q < 4; ++q) {
                int bin = (int)di[q]; if (bin > 64) bin = 64;
                atomicAdd(&lh[bin], 1);
                unsigned int a = dov[q] < 1u ? 1u : dov[q];
                unsigned int b = di[q] < 1u ? 1u : di[q];
                float fa = 1.0f / sqrtf((float)a);
                float fb = 1.0f / sqrtf((float)b);
                pns[q] = fa; pnd[q] = fb; pcc[q] = fa * fb;
            }
            *(float4*)(ns + (wid << 2)) = vns;
            *(float4*)(nd + (wid << 2)) = vnd;
            *(float4*)(cc + (wid << 2)) = vcc;
        }
    }
    __syncthreads();
    if (t < 65) dparts[blockIdx.x * 65 + t] = lh[t];
}

// ---------------- counting-sort scan (DESCENDING degree) ----------------
__global__ void k_dscan(const int* __restrict__ dparts, int* __restrict__ offs) {
    __shared__ int colsum[65], binbase[65];
    int t = threadIdx.x;
    if (t < 65) {
        int s = 0;
        for (int b = 0; b < P2BLOCKS; ++b) s += dparts[b * 65 + t];
        colsum[t] = s;
    }
    __syncthreads();
    if (t == 0) {
        int run = 0;
        for (int k = 64; k >= 0; --k) { binbase[k] = run; run += colsum[k]; }
    }
    __syncthreads();
    if (t < 65) {
        int run = binbase[t];
        for (int b = 0; b < P2BLOCKS; ++b) { offs[b * 65 + t] = run; run += dparts[b * 65 + t]; }
    }
}

// ---------------- scatter: perm/inv + permuted degree & norm arrays ----------------
__global__ void k_dscatter(const int* __restrict__ deg_in, const int* __restrict__ offs,
                           const float* __restrict__ cc, const float* __restrict__ ns,
                           const float* __restrict__ nd,
                           int* __restrict__ perm, int* __restrict__ inv,
                           int* __restrict__ degP, float* __restrict__ ccP,
                           float* __restrict__ nsP, float* __restrict__ ndP) {
    __shared__ int off[65];
    int t = threadIdx.x;
    if (t < 65) off[t] = offs[blockIdx.x * 65 + t];
    __syncthreads();
    int wid = blockIdx.x * 64 + t;
    if (t < 64 && wid < HWORDS) {
        int4 d4 = *(const int4*)(deg_in + (wid << 2));
        int dd[4] = {d4.x, d4.y, d4.z, d4.w};
#pragma unroll
        for (int k = 0; k < 4; ++k) {
            int node = (wid << 2) + k;
            int bin = dd[k] > 64 ? 64 : dd[k];
            int slot = atomicAdd(&off[bin], 1);
            perm[slot] = node; inv[node] = slot;
            degP[slot] = dd[k];
            ccP[slot] = cc[node]; nsP[slot] = ns[node]; ndP[slot] = nd[node];
        }
    }
}

// ---------------- fill csr (renumbered space) using LDS atomics only ----------------
__global__ void k_fill(const int* __restrict__ src, const int* __restrict__ dst,
                       const unsigned int* __restrict__ prefix,
                       const int* __restrict__ inv,
                       unsigned short* __restrict__ csr) {
    __shared__ unsigned int h[HWORDS];
    int t = threadIdx.x;
    const unsigned int* prow = prefix + (size_t)blockIdx.x * HWORDS;
    for (int w = t; w < HWORDS; w += 256) h[w] = prow[w];
    __syncthreads();
    int base = blockIdx.x * HCHUNK;
    for (int i = t; i < HCHUNK; i += 256) {
        int s = src[base + i], d = dst[base + i];
        int sh = (d & 3) << 3;
        unsigned int old = atomicAdd(&h[d >> 2], 1u << sh);
        int slot = (int)((old >> sh) & 0xffu);
        csr[((size_t)inv[d] << 6) + slot] = (unsigned short)inv[s];
    }
}

// ---------------- dense GEMM, 32-row tiles: Y[inv[row]] = ns[row] ∘ (X @ W13) ----------
// 1563 blocks (~6/CU, vs 782 = 3/CU at 64-row tiles -> was grid-bound at 19%
// occupancy). Simple 2-sync K-loop, no launch_bounds, no prefetch registers
// (round-11's K-split+dbuf+launch_bounds forced ~160 MB scratch spill traffic).
__global__ void k_gemm(const float* __restrict__ X, const float* __restrict__ W13,
                       const float* __restrict__ ns, const int* __restrict__ inv,
                       float* __restrict__ Y) {
    __shared__ float As[16][34];   // [k][row], pad->A-store 2-way (free), A-load bcast
    __shared__ float Bs[16][64];
    int tid = threadIdx.x;
    int tx = tid & 15, ty = tid >> 4;        // ty 0..15: two rows each
    int row0 = blockIdx.x * 32;
    float acc[2][4];
#pragma unroll
    for (int i = 0; i < 2; ++i)
#pragma unroll
        for (int j = 0; j < 4; ++j) acc[i][j] = 0.f;

    int lr = tid & 31;                       // row in tile
    int lk2 = (tid >> 5) << 1;               // k offset 0,2,..,14
    int arow = row0 + lr;
    if (arow > N_NODES - 1) arow = N_NODES - 1;   // clamp: garbage rows never stored

    for (int k0 = 0; k0 < DIN; k0 += 16) {
        float2 a = *(const float2*)(X + (size_t)arow * DIN + k0 + lk2);
        As[lk2][lr] = a.x; As[lk2 + 1][lr] = a.y;
        float4 b = *(const float4*)(W13 + (size_t)(k0 + ty) * DOUT + (tx << 2));
        *(float4*)&Bs[ty][tx << 2] = b;
        __syncthreads();
#pragma unroll
        for (int k = 0; k < 16; ++k) {
            float2 av = *(const float2*)&As[k][ty << 1];
            float4 bv = *(const float4*)&Bs[k][tx << 2];
            float ar[2] = {av.x, av.y};
            float br[4] = {bv.x, bv.y, bv.z, bv.w};
#pragma unroll
            for (int i = 0; i < 2; ++i)
#pragma unroll
                for (int j = 0; j < 4; ++j) acc[i][j] += ar[i] * br[j];
        }
        __syncthreads();
    }
    int qq = tx >> 2;
    int co = (tx & 3) << 2;
#pragma unroll
    for (int i = 0; i < 2; ++i) {
        int row = row0 + (ty << 1) + i;
        if (row < N_NODES) {
            float nsr = ns[row];
            int prow = inv[row];
            float4 o;
            o.x = acc[i][0] * nsr; o.y = acc[i][1] * nsr;
            o.z = acc[i][2] * nsr; o.w = acc[i][3] * nsr;
            *(float4*)(Y + (size_t)qq * SLICE + ((size_t)prow << 4) + co) = o;
        }
    }
}

// ---------------- sliced pull SpMM, degree-sorted: 4 nodes x 4 edge-slots x float4 ------
// Loop bound m = pad4(degP[node0]) (group max, descending sort). Wave-uniform m
// branches to fully-unrolled paths (all gathers issued back-to-back, <=8 in
// flight). LDS rows TRANSPOSED [entry*4 + node] -> conflict-free ds_read_u16.
// MODE 0: y = cc*acc + ns*bb[col]; MODE 1: y = cc*acc;
// MODE 2: out[perm[node]] = nd*acc + b3[col]  (row-major, original numbering).

template <int MODE>
__launch_bounds__(256, 8)
__global__ void k_spmm(const float* __restrict__ xs, float* __restrict__ ys,
                       const unsigned short* __restrict__ csr,
                       const int* __restrict__ degP,
                       const float* __restrict__ ccP, const float* __restrict__ nsP,
                       const float* __restrict__ ndP,
                       const float* __restrict__ bb, const float* __restrict__ b3,
                       const int* __restrict__ perm) {
    __shared__ unsigned short rows[4][256];     // [wave][entry*4 + node] = 2 KB
    int wid  = threadIdx.x >> 6;
    int lane = threadIdx.x & 63;
    int q    = (blockIdx.x & 7) >> 1;
    int half = blockIdx.x & 1;
    int g    = (blockIdx.x >> 3) * 8 + wid * 2 + half;   // 4-node group id
    if (g >= NGROUPS) return;
    int node0 = g << 2;

    // stage 4 csr rows (4 x 128 B) into LDS, transposed: lane (nn,sl) loads
    // entries 4sl..4sl+3 of node nn and writes them at [(4sl+k)*4 + nn].
    int nn = lane >> 4, sl = lane & 15;
    const uint2* crow = (const uint2*)(csr + ((size_t)(node0 + nn) << 6)) + sl;
    uint2 rv = *crow;
    unsigned short* bp = &rows[wid][(sl << 4) + nn];
    bp[0]  = (unsigned short)(rv.x & 0xffffu);
    bp[4]  = (unsigned short)(rv.x >> 16);
    bp[8]  = (unsigned short)(rv.y & 0xffffu);
    bp[12] = (unsigned short)(rv.y >> 16);

    int n0u = __builtin_amdgcn_readfirstlane(node0);
    int m = (degP[n0u] + 3) & ~3;        // group max (descending sort), pad4

    int n = lane >> 4, e = (lane >> 2) & 3, c4 = lane & 3;
    const unsigned short* rd = &rows[wid][(e << 2) + n];   // entry (e+4T) at rd[16T]
    const float* xq = xs + (size_t)q * SLICE + (c4 << 2);

    float ax = 0.f, ay = 0.f, az = 0.f, aw = 0.f;
#define LDV(T) const float4 v##T = *(const float4*)(xq + ((size_t)rd[16 * (T)] << 4))
#define ACCV(T) ax += v##T.x; ay += v##T.y; az += v##T.z; aw += v##T.w
    if (m <= 4) {
        LDV(0); ACCV(0);
    } else if (m <= 8) {
        LDV(0); LDV(1);
        ACCV(0); ACCV(1);
    } else if (m <= 12) {
        LDV(0); LDV(1); LDV(2);
        ACCV(0); ACCV(1); ACCV(2);
    } else if (m <= 16) {
        LDV(0); LDV(1); LDV(2); LDV(3);
        ACCV(0); ACCV(1); ACCV(2); ACCV(3);
    } else if (m <= 20) {
        LDV(0); LDV(1); LDV(2); LDV(3); LDV(4);
        ACCV(0); ACCV(1); ACCV(2); ACCV(3); ACCV(4);
    } else if (m <= 24) {
        LDV(0); LDV(1); LDV(2); LDV(3); LDV(4); LDV(5);
        ACCV(0); ACCV(1); ACCV(2); ACCV(3); ACCV(4); ACCV(5);
    } else if (m <= 28) {
        LDV(0); LDV(1); LDV(2); LDV(3); LDV(4); LDV(5); LDV(6);
        ACCV(0); ACCV(1); ACCV(2); ACCV(3); ACCV(4); ACCV(5); ACCV(6);
    } else if (m <= 32) {
        LDV(0); LDV(1); LDV(2); LDV(3); LDV(4); LDV(5); LDV(6); LDV(7);
        ACCV(0); ACCV(1); ACCV(2); ACCV(3); ACCV(4); ACCV(5); ACCV(6); ACCV(7);
    } else {
        for (int j2 = 0; j2 < m; j2 += 4) {
            const float4 a = *(const float4*)(xq + ((size_t)rd[j2 << 2] << 4));
            ax += a.x; ay += a.y; az += a.z; aw += a.w;
        }
    }
#undef LDV
#undef ACCV
    // reduce over edge-slots e (lane bits 2..3)
    ax += __shfl_xor(ax, 4);  ay += __shfl_xor(ay, 4);
    az += __shfl_xor(az, 4);  aw += __shfl_xor(aw, 4);
    ax += __shfl_xor(ax, 8);  ay += __shfl_xor(ay, 8);
    az += __shfl_xor(az, 8);  aw += __shfl_xor(aw, 8);

    int nodeL = node0 + n;
    int colq  = (q << 4) + (c4 << 2);
    float4 r;
    if (MODE == 0) {
        float cv = ccP[nodeL], nv = nsP[nodeL];
        float4 bv = *(const float4*)(bb + colq);
        r.x = cv * ax + nv * bv.x; r.y = cv * ay + nv * bv.y;
        r.z = cv * az + nv * bv.z; r.w = cv * aw + nv * bv.w;
    } else if (MODE == 1) {
        float cv = ccP[nodeL];
        r.x = cv * ax; r.y = cv * ay; r.z = cv * az; r.w = cv * aw;
    } else {
        float dv = ndP[nodeL];
        float4 bv = *(const float4*)(b3 + colq);
        r.x = dv * ax + bv.x; r.y = dv * ay + bv.y;
        r.z = dv * az + bv.z; r.w = dv * aw + bv.w;
    }
    if (e == 0) {
        if (MODE == 2) {
            int orow = perm[nodeL];
            *(float4*)(ys + ((size_t)orow << 6) + colq) = r;
        } else {
            *(float4*)(ys + (size_t)q * SLICE + ((size_t)nodeL << 4) + (c4 << 2)) = r;
        }
    }
}

// ---------------- launcher ----------------

extern "C" void kernel_launch(void* const* d_in, const int* in_sizes, int n_in,
                              void* d_out, int out_size, void* d_ws, size_t ws_size,
                              hipStream_t stream) {
    const float* X   = (const float*)d_in[0];
    const int*   src = (const int*)d_in[1];
    const int*   dst = (const int*)d_in[2];
    const float* W1  = (const float*)d_in[3];
    const float* b1  = (const float*)d_in[4];
    const float* W3  = (const float*)d_in[5];
    const float* b3  = (const float*)d_in[6];
    float* out = (float*)d_out;

    char* ws = (char*)d_ws;
    size_t off = 0;
    auto alloc = [&](size_t bytes) -> void* {
        void* p = ws + off;
        off = (off + bytes + 255) & ~(size_t)255;
        return p;
    };
    unsigned int*   pS     = (unsigned int*)alloc((size_t)HBLOCKS * HWORDS * 4);
    unsigned int*   pD     = (unsigned int*)alloc((size_t)HBLOCKS * HWORDS * 4);
    unsigned int*   pref   = (unsigned int*)alloc((size_t)HBLOCKS * HWORDS * 4);
    float*          Y0     = (float*)alloc(SLICE * 4 * 4);
    float*          Y1     = (float*)alloc(SLICE * 4 * 4);
    unsigned short* csr    = (unsigned short*)alloc((size_t)N_NODES * CSTRIDE * 2);
    int*            deg_in = (int*)alloc((size_t)N_NODES * 4);
    float*          ns     = (float*)alloc((size_t)N_NODES * 4);
    float*          nd     = (float*)alloc((size_t)N_NODES * 4);
    float*          cc     = (float*)alloc((size_t)N_NODES * 4);
    int*            perm   = (int*)alloc((size_t)N_NODES * 4);
    int*            inv    = (int*)alloc((size_t)N_NODES * 4);
    int*            degP   = (int*)alloc((size_t)N_NODES * 4);
    float*          ccP    = (float*)alloc((size_t)N_NODES * 4);
    float*          nsP    = (float*)alloc((size_t)N_NODES * 4);
    float*          ndP    = (float*)alloc((size_t)N_NODES * 4);
    int*            dparts = (int*)alloc((size_t)P2BLOCKS * 65 * 4);
    int*            offs   = (int*)alloc((size_t)P2BLOCKS * 65 * 4);
    float*          W13    = (float*)alloc((size_t)DIN * DOUT * 4);
    float*          bb     = (float*)alloc(DOUT * 4);

    const int sblk = 1563 * 8;   // 12504 blocks -> 12500 groups x 4 slices

    k_setup<<<SB_TOT, 256, 0, stream>>>(src, dst, pS, pD, (unsigned int*)csr,
                                        W1, b1, W3, W13, bb, Y0, Y1);
    k_hpre<<<P2BLOCKS, 256, 0, stream>>>(pS, pD, pref, deg_in, ns, nd, cc, dparts);
    k_dscan<<<1, 128, 0, stream>>>(dparts, offs);
    k_dscatter<<<P2BLOCKS, 128, 0, stream>>>(deg_in, offs, cc, ns, nd,
                                             perm, inv, degP, ccP, nsP, ndP);
    k_fill<<<HBLOCKS, 256, 0, stream>>>(src, dst, pref, inv, csr);

    // Y0 = ns ∘ (X @ (W1@W3)), column-sliced, renumbered rows (32-row tiles)
    k_gemm<<<(N_NODES + 31) / 32, 256, 0, stream>>>(X, W13, ns, inv, Y0);

    // 6 propagation passes; bias bb injected in pass 1, b3 in pass 6
    k_spmm<0><<<sblk, 256, 0, stream>>>(Y0, Y1, csr, degP, ccP, nsP, ndP, bb, b3, perm);
    k_spmm<1><<<sblk, 256, 0, stream>>>(Y1, Y0, csr, degP, ccP, nsP, ndP, bb, b3, perm);
    k_spmm<1><<<sblk, 256, 0, stream>>>(Y0, Y1, csr, degP, ccP, nsP, ndP, bb, b3, perm);
    k_spmm<1><<<sblk, 256, 0, stream>>>(Y1, Y0, csr, degP, ccP, nsP, ndP, bb, b3, perm);
    k_spmm<1><<<sblk, 256, 0, stream>>>(Y0, Y1, csr, degP, ccP, nsP, ndP, bb, b3, perm);
    k_spmm<2><<<sblk, 256, 0, stream>>>(Y1, out, csr, degP, ccP, nsP, ndP, bb, b3, perm);
}